// Round 3
// baseline (202.101 us; speedup 1.0000x reference)
//
#include <hip/hip_runtime.h>

typedef __attribute__((ext_vector_type(8))) short short8;   // 8 bf16 (4 VGPRs)
typedef __attribute__((ext_vector_type(4))) float f32x4;    // MFMA accumulator
typedef __attribute__((ext_vector_type(4))) float vf4;      // vector float4

// pack two positive floats to bf16x2 with round-half-up: +0x8000 then take hi16
__device__ __forceinline__ unsigned pk_bf16(float lo, float hi) {
    const unsigned ul = __float_as_uint(lo) + 0x8000u;
    const unsigned uh = __float_as_uint(hi) + 0x8000u;
    return __builtin_amdgcn_perm(uh, ul, 0x07060302u);
}

// ---------------- Kernel 1: softmax + MFMA sub, pure streaming ----------------
// One wave = one batch element. No LDS, no tail: blocks retire immediately so
// the CU always has fresh waves issuing HBM loads.
__global__ __launch_bounds__(256) void sub_kernel(
    const float* __restrict__ logits,   // [B,16,256]
    const int*   __restrict__ tidx,     // [B,16]
    const float* __restrict__ phon,     // [256,256], symmetric
    float*       __restrict__ sub_ws,   // [B,16,16] row-major
    float*       __restrict__ p0_ws,    // [B]
    int B)
{
    const int lane = threadIdx.x & 63;
    const int wv   = threadIdx.x >> 6;
    int b = blockIdx.x * 4 + wv;
    if (b >= B) b = B - 1;              // duplicate work; idempotent stores

    const int t = lane & 15;            // softmax row / MFMA M
    const int q = lane >> 4;            // K quad

    const int idxn = tidx[b * 16 + t];  // lane t owns sub column t -> phon row idxn
    const int idx0 = __shfl(idxn, 0);   // uniform
    const int c0 = idx0 >> 5;
    const int q0 = (idx0 >> 3) & 3;
    const int j0 = idx0 & 7;

    const float* lp = logits + (size_t)b * 4096 + t * 256 + q * 8;
    const float* bp = phon   + (size_t)idxn * 256 + q * 8;

    // hoist all logits loads: 16 x dwordx4 in flight per wave
    vf4 xv[16];
    #pragma unroll
    for (int c = 0; c < 8; ++c) {
        xv[2 * c]     = *(const vf4*)(lp + c * 32);
        xv[2 * c + 1] = *(const vf4*)(lp + c * 32 + 4);
    }

    f32x4 acc = {0.f, 0.f, 0.f, 0.f};
    float zsum = 0.f;
    float e0cap = 0.f;

    #pragma unroll
    for (int c = 0; c < 8; ++c) {
        const vf4 x0 = xv[2 * c];
        const vf4 x1 = xv[2 * c + 1];
        const vf4 y0 = *(const vf4*)(bp + c * 32);
        const vf4 y1 = *(const vf4*)(bp + c * 32 + 4);

        const float e0_ = __expf(x0[0]), e1_ = __expf(x0[1]);
        const float e2_ = __expf(x0[2]), e3_ = __expf(x0[3]);
        const float e4_ = __expf(x1[0]), e5_ = __expf(x1[1]);
        const float e6_ = __expf(x1[2]), e7_ = __expf(x1[3]);
        zsum += ((e0_ + e1_) + (e2_ + e3_)) + ((e4_ + e5_) + (e6_ + e7_));

        if (c == c0) {                  // wave-uniform branch, taken once
            const float a01 = (j0 & 1) ? e1_ : e0_;
            const float a23 = (j0 & 1) ? e3_ : e2_;
            const float a45 = (j0 & 1) ? e5_ : e4_;
            const float a67 = (j0 & 1) ? e7_ : e6_;
            const float b03 = (j0 & 2) ? a23 : a01;
            const float b47 = (j0 & 2) ? a67 : a45;
            const float sel = (j0 & 4) ? b47 : b03;
            if ((t == 0) && (q == q0)) e0cap = sel;
        }

        union { short8 s; unsigned u[4]; } A, Bb;
        A.u[0] = pk_bf16(e0_, e1_); A.u[1] = pk_bf16(e2_, e3_);
        A.u[2] = pk_bf16(e4_, e5_); A.u[3] = pk_bf16(e6_, e7_);
        Bb.u[0] = pk_bf16(y0[0], y0[1]); Bb.u[1] = pk_bf16(y0[2], y0[3]);
        Bb.u[2] = pk_bf16(y1[0], y1[1]); Bb.u[3] = pk_bf16(y1[2], y1[3]);

        // D[row=q*4+r][col=t] += A[t][k]*B[k][col], k = c*32 + q*8 + j
        acc = __builtin_amdgcn_mfma_f32_16x16x32_bf16(A.s, Bb.s, acc, 0, 0, 0);
    }

    // Z_t reduce across the 4 quads of row t
    zsum += __shfl_xor(zsum, 16);
    zsum += __shfl_xor(zsum, 32);
    const float rz = 1.0f / zsum;

    // first-char probability in fp32
    const float e0b = __shfl(e0cap, q0 * 16);
    const float rz0 = __shfl(rz, 0);
    if (lane == 0) p0_ws[b] = e0b * rz0;

    // normalize rows and stream sub out row-major
    #pragma unroll
    for (int r = 0; r < 4; ++r) {
        const float rzr = __shfl(rz, q * 4 + r);   // lane (q*4+r) holds 1/Z_row
        sub_ws[(size_t)b * 256 + (q * 4 + r) * 16 + t] = acc[r] * rzr;
    }
}

// ---------------- Kernel 2: packed anti-diagonal DP ----------------
// 256 threads = 4 waves = 16 DP problems per block; no idle-lane waste beyond
// the intrinsic 16-of-16 packing (4 problems per wave).
__global__ __launch_bounds__(256) void dp_kernel(
    const float* __restrict__ sub_ws,   // [B,16,16]
    const float* __restrict__ p0_ws,    // [B]
    float*       __restrict__ out,      // [B]
    int B)
{
    __shared__ float s[16][16][17];     // [problem][row][col+pad]

    const int tid = threadIdx.x;
    const int bb  = blockIdx.x * 16;

    // cooperative coalesced load: thread i -> batch g=i>>4, row=i&15, 16 floats
    {
        const int g = tid >> 4, row = tid & 15;
        int bsrc = bb + g; if (bsrc >= B) bsrc = B - 1;
        const vf4* src = (const vf4*)(sub_ws + (size_t)bsrc * 256 + row * 16);
        #pragma unroll
        for (int c4 = 0; c4 < 4; ++c4) {
            const vf4 v = src[c4];
            s[g][row][c4 * 4 + 0] = v[0];
            s[g][row][c4 * 4 + 1] = v[1];
            s[g][row][c4 * 4 + 2] = v[2];
            s[g][row][c4 * 4 + 3] = v[3];
        }
    }
    __syncthreads();

    const int lane = tid & 63;
    const int wv   = tid >> 6;
    const int g    = wv * 4 + (lane >> 4);  // problem index within block
    const int tl   = lane & 15;
    const int j    = tl + 1;                // DP column

    // shfl_up across a 16-lane group boundary only feeds lanes with j==1,
    // which override left/diag with boundary values.
    float P1 = 0.f, P2 = 0.f;
    #pragma unroll
    for (int d = 2; d <= 32; ++d) {
        const float lnv = __shfl_up(P1, 1);     // left  = cell(i, j-1)
        const float dgv = __shfl_up(P2, 1);     // diag  = cell(i-1, j-1)
        const int i = d - j;
        const float up   = (i == 1) ? 10.0f * (float)j : P1;
        const float left = (j == 1) ? 10.0f * (float)i : lnv;
        const float diag = (i == 1) ? 10.0f * (float)(j - 1)
                         : ((j == 1) ? 10.0f * (float)(i - 1) : dgv);
        int row = i - 1; row = row < 0 ? 0 : (row > 15 ? 15 : row);
        const float sv = s[g][row][tl];
        const float a  = up   + 10.0f;
        const float bc = left + 10.0f;
        const float cc = diag + sv;
        const float mn = fminf(a, fminf(bc, cc));
        const float sm = __expf(mn - a) + __expf(mn - bc) + __expf(mn - cc);
        const float val = mn - __logf(sm);
        const bool act = (i >= 1) && (i <= 16);
        P2 = act ? P1 : P2;
        P1 = act ? val : P1;
    }

    const int gb = bb + g;
    if (tl == 15 && gb < B) {
        out[gb] = P1 + 10.0f * (1.0f - p0_ws[gb]);  // dp(16,16) + 10*(1-p0)
    }
}

extern "C" void kernel_launch(void* const* d_in, const int* in_sizes, int n_in,
                              void* d_out, int out_size, void* d_ws, size_t ws_size,
                              hipStream_t stream) {
    const float* logits = (const float*)d_in[0];
    const int*   tidx   = (const int*)d_in[1];
    const float* phon   = (const float*)d_in[2];
    float* out = (float*)d_out;

    const int B = in_sizes[0] / (16 * 256);
    float* sub_ws = (float*)d_ws;                    // B*256 floats (8 MB)
    float* p0_ws  = sub_ws + (size_t)B * 256;        // B floats

    const int blocks1 = (B + 3) / 4;                 // 4 waves = 4 batches/block
    hipLaunchKernelGGL(sub_kernel, dim3(blocks1), dim3(256), 0, stream,
                       logits, tidx, phon, sub_ws, p0_ws, B);

    const int blocks2 = (B + 15) / 16;               // 16 DP problems/block
    hipLaunchKernelGGL(dp_kernel, dim3(blocks2), dim3(256), 0, stream,
                       sub_ws, p0_ws, out, B);
}

// Round 4
// 195.398 us; speedup vs baseline: 1.0343x; 1.0343x over previous
//
#include <hip/hip_runtime.h>

typedef __attribute__((ext_vector_type(8))) short short8;   // 8 bf16 (4 VGPRs)
typedef __attribute__((ext_vector_type(4))) float f32x4;    // MFMA accumulator

// pack two positive floats to bf16x2 with round-half-up: +0x8000 then take hi16
__device__ __forceinline__ unsigned pk_bf16(float lo, float hi) {
    const unsigned ul = __float_as_uint(lo) + 0x8000u;
    const unsigned uh = __float_as_uint(hi) + 0x8000u;
    return __builtin_amdgcn_perm(uh, ul, 0x07060302u);
}

#define SR 68   // LDS row stride in u32 (4*odd: floor-optimal b128 frag reads)

// One wave = one batch. All global loads lane-contiguous; layout shuffle via LDS.
// K processed in 2 halves of 128 to bound LDS at ~39 KB/block (4 blocks/CU).
__global__ __launch_bounds__(256) void rhyme_kernel(
    const float* __restrict__ logits,   // [B,16,256]
    const int*   __restrict__ tidx,     // [B,16]
    const float* __restrict__ phon,     // [256,256], symmetric
    float*       __restrict__ out,      // [B]
    int B)
{
    __shared__ __align__(16) unsigned A_l[4][16 * SR];   // exp(logits) bf16 pairs
    __shared__ __align__(16) unsigned B_l[4][16 * SR];   // phon rows   bf16 pairs
    __shared__ float sub_lds[4][16][17];
    __shared__ float p0e[4];            // exp(logit[0][idx0]) fp32
    __shared__ float p0s[4];            // first-char prob

    const int lane = threadIdx.x & 63;
    const int wv   = threadIdx.x >> 6;
    int b = blockIdx.x * 4 + wv;
    if (b >= B) b = B - 1;              // duplicate work; stores gated later

    const int t = lane & 15;            // MFMA M row / B column owner
    const int q = lane >> 4;            // K quad

    const int idxn = tidx[b * 16 + t];  // lane t owns sub column t
    const int idx0 = __shfl(idxn, 0);
    const int h0 = idx0 >> 7;           // which K-half holds v=idx0
    const int l0 = (idx0 >> 1) & 63;    // which lane loads it
    const int e0odd = idx0 & 1;

    unsigned* Aw = &A_l[wv][0];
    unsigned* Bw = &B_l[wv][0];

    union { short8 s; unsigned u[4]; } ones;
    ones.u[0] = ones.u[1] = ones.u[2] = ones.u[3] = 0x3F803F80u;  // bf16 1.0 x2

    f32x4 acc  = {0.f, 0.f, 0.f, 0.f};
    f32x4 accz = {0.f, 0.f, 0.f, 0.f};

    const float* lbase = logits + (size_t)b * 4096;

    for (int h = 0; h < 2; ++h) {
        // ---- stage B half: 16 coalesced 512-B row reads (8 lines/instr) ----
        #pragma unroll
        for (int r = 0; r < 16; ++r) {
            const int row = __shfl(idxn, r);            // wave-uniform
            const float2 v = *(const float2*)(phon + row * 256 + h * 128 + lane * 2);
            Bw[r * SR + lane] = pk_bf16(v.x, v.y);      // b32 write, 2-way (free)
        }
        // ---- stage A half: coalesced loads + exp + pack ----
        #pragma unroll
        for (int k = 0; k < 16; ++k) {
            const float2 v = *(const float2*)(lbase + k * 256 + h * 128 + lane * 2);
            const float ea = __expf(v.x);
            const float eb = __expf(v.y);
            if (k == 0 && h == h0 && lane == l0)
                p0e[wv] = e0odd ? eb : ea;              // fp32 capture
            Aw[k * SR + lane] = pk_bf16(ea, eb);
        }
        __asm__ volatile("s_waitcnt lgkmcnt(0)" ::: "memory");

        // ---- MFMA: frag reads are b128, uniform over all 8 bank groups ----
        #pragma unroll
        for (int c = 0; c < 4; ++c) {
            const short8 af = *(const short8*)(Aw + t * SR + c * 16 + q * 4);
            const short8 bf = *(const short8*)(Bw + t * SR + c * 16 + q * 4);
            acc  = __builtin_amdgcn_mfma_f32_16x16x32_bf16(af, bf,     acc,  0, 0, 0);
            accz = __builtin_amdgcn_mfma_f32_16x16x32_bf16(af, ones.s, accz, 0, 0, 0);
        }
        __asm__ volatile("s_waitcnt lgkmcnt(0)" ::: "memory");  // WAR vs next half
    }

    // acc[r] = sub_unnorm[q*4+r][t], accz[r] = Z_{q*4+r}: same slot -> no shuffles
    #pragma unroll
    for (int r = 0; r < 4; ++r)
        sub_lds[wv][q * 4 + r][t] = acc[r] / accz[r];

    if (lane == 0)
        p0s[wv] = p0e[wv] / accz[0];    // lane 0 holds Z_0; p0e from LDS (wait done)

    __syncthreads();
    if (wv != 0) return;                // wave 0 runs the block's 4 DPs merged

    // Anti-diagonal DP, 4 problems packed: group g = lane>>4, column j = (lane&15)+1.
    const int g  = lane >> 4;
    const int tl = lane & 15;
    const int j  = tl + 1;
    float P1 = 0.f, P2 = 0.f;
    #pragma unroll
    for (int d = 2; d <= 32; ++d) {
        const float lnv = __shfl_up(P1, 1);     // left  = cell(i, j-1)
        const float dgv = __shfl_up(P2, 1);     // diag  = cell(i-1, j-1)
        const int i = d - j;
        const float up   = (i == 1) ? 10.0f * (float)j : P1;
        const float left = (j == 1) ? 10.0f * (float)i : lnv;
        const float diag = (i == 1) ? 10.0f * (float)(j - 1)
                         : ((j == 1) ? 10.0f * (float)(i - 1) : dgv);
        int row = i - 1; row = row < 0 ? 0 : (row > 15 ? 15 : row);
        const float sv = sub_lds[g][row][tl];
        const float a  = up   + 10.0f;
        const float bc = left + 10.0f;
        const float cc = diag + sv;
        const float mn = fminf(a, fminf(bc, cc));
        const float sm = __expf(mn - a) + __expf(mn - bc) + __expf(mn - cc);
        const float val = mn - __logf(sm);
        const bool act = (i >= 1) && (i <= 16);
        P2 = act ? P1 : P2;
        P1 = act ? val : P1;
    }

    const int gb = blockIdx.x * 4 + g;
    if (tl == 15 && gb < B) {
        out[gb] = P1 + 10.0f * (1.0f - p0s[g]);  // dp(16,16) + 10*(1-p0)
    }
}

extern "C" void kernel_launch(void* const* d_in, const int* in_sizes, int n_in,
                              void* d_out, int out_size, void* d_ws, size_t ws_size,
                              hipStream_t stream) {
    const float* logits = (const float*)d_in[0];
    const int*   tidx   = (const int*)d_in[1];
    const float* phon   = (const float*)d_in[2];
    float* out = (float*)d_out;

    const int B = in_sizes[0] / (16 * 256);
    const int blocks = (B + 3) / 4;          // 4 waves = 4 batches per block
    hipLaunchKernelGGL(rhyme_kernel, dim3(blocks), dim3(256), 0, stream,
                       logits, tidx, phon, out, B);
}